// Round 1
// baseline (832.987 us; speedup 1.0000x reference)
//
#include <hip/hip_runtime.h>
#include <hip/hip_bf16.h>

#define T_TOK 16384
#define D_DIM 4096
#define E_EXP 256
#define G_GRP 8
#define EPG_C 32
#define NSEL 4

// ---------------------------------------------------------------------------
// Kernel 0: zero the 512-float accumulator region of the workspace
// ---------------------------------------------------------------------------
__global__ void zero512_kernel(float* __restrict__ p) {
    p[threadIdx.x] = 0.0f;
}

// ---------------------------------------------------------------------------
// Kernel 1: logits[T,E] = x[T,D] @ W[E,D]^T   (fp32, vector FMA)
// Block: 256 threads, tile = 32 tokens x 256 experts, BK = 32.
// Per thread: 4 experts (stride 64) x 8 tokens = 32 accumulators.
// ---------------------------------------------------------------------------
#define BK 32
#define MT 32

__global__ __launch_bounds__(256, 2)
void gemm_kernel(const float* __restrict__ x, const float* __restrict__ W,
                 float* __restrict__ logits) {
    // sXt: [k][token] so compute reads are b128-aligned broadcasts.
    __shared__ float sXt[BK][MT];          // 4 KB
    __shared__ float sW[E_EXP][BK + 1];    // 33.8 KB, +1 pad: reads 2-way (free)
    const int t = threadIdx.x;
    const int tok0 = blockIdx.x * MT;

    const int tcol = t & 63;   // expert base (lane-contiguous -> coalesced C store)
    const int trow = t >> 6;   // token sub-block (8 tokens)

    const int lr = t >> 3;        // 0..31 staging row
    const int lc = (t & 7) * 4;   // 0,4,..,28 staging col (float4)

    float acc[4][8];
    #pragma unroll
    for (int i = 0; i < 4; ++i)
        #pragma unroll
        for (int m = 0; m < 8; ++m) acc[i][m] = 0.0f;

    const float* xrow = x + (size_t)(tok0 + lr) * D_DIM + lc;

    for (int kb = 0; kb < D_DIM; kb += BK) {
        // stage x tile (32 tokens x 32 k), transposed into LDS
        {
            const float4 v = *(const float4*)(xrow + kb);
            sXt[lc + 0][lr] = v.x;
            sXt[lc + 1][lr] = v.y;
            sXt[lc + 2][lr] = v.z;
            sXt[lc + 3][lr] = v.w;
        }
        // stage W tile (256 experts x 32 k)
        #pragma unroll
        for (int j = 0; j < 8; ++j) {
            const int r = lr + 32 * j;
            const float4 v = *(const float4*)(W + (size_t)r * D_DIM + kb + lc);
            sW[r][lc + 0] = v.x;
            sW[r][lc + 1] = v.y;
            sW[r][lc + 2] = v.z;
            sW[r][lc + 3] = v.w;
        }
        __syncthreads();

        #pragma unroll 8
        for (int kk = 0; kk < BK; ++kk) {
            const float4 xa = *(const float4*)&sXt[kk][trow * 8];
            const float4 xb = *(const float4*)&sXt[kk][trow * 8 + 4];
            const float xs[8] = {xa.x, xa.y, xa.z, xa.w, xb.x, xb.y, xb.z, xb.w};
            #pragma unroll
            for (int i = 0; i < 4; ++i) {
                const float w = sW[tcol + 64 * i][kk];
                #pragma unroll
                for (int m = 0; m < 8; ++m)
                    acc[i][m] = fmaf(xs[m], w, acc[i][m]);
            }
        }
        __syncthreads();
    }

    #pragma unroll
    for (int i = 0; i < 4; ++i) {
        const int e = tcol + 64 * i;
        #pragma unroll
        for (int m = 0; m < 8; ++m)
            logits[(size_t)(tok0 + trow * 8 + m) * E_EXP + e] = acc[i][m];
    }
}

// ---------------------------------------------------------------------------
// Kernel 2: per-token softmax + grouped top-k + stats accumulation.
// One wave (64 lanes) per token; lane l owns experts 4l..4l+3; group = l>>3.
// ---------------------------------------------------------------------------
__device__ __forceinline__ float wave_max(float v) {
    #pragma unroll
    for (int off = 32; off >= 1; off >>= 1)
        v = fmaxf(v, __shfl_xor(v, off, 64));
    return v;
}
__device__ __forceinline__ float wave_sum(float v) {
    #pragma unroll
    for (int off = 32; off >= 1; off >>= 1)
        v += __shfl_xor(v, off, 64);
    return v;
}

#define TOKS_PER_WAVE 16

__global__ __launch_bounds__(256)
void router_kernel(const float* __restrict__ logits,
                   float* __restrict__ out_w,
                   float* __restrict__ out_id,
                   float* __restrict__ g_psum,
                   float* __restrict__ g_cnt) {
    __shared__ float lds_psum[E_EXP];
    __shared__ float lds_cnt[E_EXP];
    const int t = threadIdx.x;
    if (t < E_EXP) { lds_psum[t] = 0.0f; lds_cnt[t] = 0.0f; }
    __syncthreads();

    const int wave = t >> 6;
    const int lane = t & 63;
    const int tok0 = blockIdx.x * (4 * TOKS_PER_WAVE) + wave * TOKS_PER_WAVE;

    float r0 = 0.f, r1 = 0.f, r2 = 0.f, r3 = 0.f;  // per-expert prob sums

    for (int it = 0; it < TOKS_PER_WAVE; ++it) {
        const int tok = tok0 + it;
        const float4 lg = *(const float4*)(logits + (size_t)tok * E_EXP + lane * 4);

        const float M = wave_max(fmaxf(fmaxf(lg.x, lg.y), fmaxf(lg.z, lg.w)));
        float p0 = expf(lg.x - M);
        float p1 = expf(lg.y - M);
        float p2 = expf(lg.z - M);
        float p3 = expf(lg.w - M);
        const float inv = 1.0f / wave_sum(p0 + p1 + p2 + p3);
        p0 *= inv; p1 *= inv; p2 *= inv; p3 *= inv;
        r0 += p0; r1 += p1; r2 += p2; r3 += p3;

        // per-lane top-2 of 4 (ties -> lowest index first, matching lax.top_k)
        const int e0 = lane * 4;
        float v1 = p0, v2 = p1; int i1 = e0, i2 = e0 + 1;
        if (p1 > p0) { v1 = p1; i1 = e0 + 1; v2 = p0; i2 = e0; }
        if (p2 > v1)      { v2 = v1; i2 = i1; v1 = p2; i1 = e0 + 2; }
        else if (p2 > v2) { v2 = p2; i2 = e0 + 2; }
        if (p3 > v1)      { v2 = v1; i2 = i1; v1 = p3; i1 = e0 + 3; }
        else if (p3 > v2) { v2 = p3; i2 = e0 + 3; }

        // merge top-2 across the 8 lanes of each group
        #pragma unroll
        for (int off = 1; off <= 4; off <<= 1) {
            const float ov1 = __shfl_xor(v1, off, 64);
            const int   oi1 = __shfl_xor(i1, off, 64);
            const float ov2 = __shfl_xor(v2, off, 64);
            const int   oi2 = __shfl_xor(i2, off, 64);
            float n1, n2; int ni1, ni2;
            const bool o_first = (ov1 > v1) || (ov1 == v1 && oi1 < i1);
            if (o_first) {
                n1 = ov1; ni1 = oi1;
                const bool s = (ov2 > v1) || (ov2 == v1 && oi2 < i1);
                n2 = s ? ov2 : v1; ni2 = s ? oi2 : i1;
            } else {
                n1 = v1; ni1 = i1;
                const bool s = (ov1 > v2) || (ov1 == v2 && oi1 < i2);
                n2 = s ? ov1 : v2; ni2 = s ? oi1 : i2;
            }
            v1 = n1; i1 = ni1; v2 = n2; i2 = ni2;
        }

        // gather all 8 groups' results to every lane
        float gv1[8], gv2[8], gsc[8]; int gi1[8], gi2[8];
        #pragma unroll
        for (int g = 0; g < 8; ++g) {
            gv1[g] = __shfl(v1, g * 8, 64);
            gv2[g] = __shfl(v2, g * 8, 64);
            gi1[g] = __shfl(i1, g * 8, 64);
            gi2[g] = __shfl(i2, g * 8, 64);
            gsc[g] = gv1[g] + gv2[g];
        }

        // top-4 groups by score (ties -> lowest group index)
        float cp[8]; int cid[8];
        int usedmask = 0;
        #pragma unroll
        for (int r = 0; r < 4; ++r) {
            float best = -1.0f; int bg = 0;
            float b1 = 0.f, b2 = 0.f; int bi1 = 0, bi2 = 0;
            #pragma unroll
            for (int g = 0; g < 8; ++g) {
                const bool ok = (((usedmask >> g) & 1) == 0) && (gsc[g] > best);
                if (ok) { best = gsc[g]; bg = g;
                          b1 = gv1[g]; b2 = gv2[g]; bi1 = gi1[g]; bi2 = gi2[g]; }
            }
            usedmask |= (1 << bg);
            cp[2 * r] = b1; cp[2 * r + 1] = b2;
            cid[2 * r] = bi1; cid[2 * r + 1] = bi2;
        }

        float wsum = 1e-9f;
        #pragma unroll
        for (int j = 0; j < 8; ++j) wsum += cp[j];
        const float winv = 1.0f / wsum;

        if (lane == 0) {
            #pragma unroll
            for (int j = 0; j < 8; ++j) {
                out_w[(size_t)tok * 8 + j] = cp[j] * winv;
                out_id[(size_t)tok * 8 + j] = (float)cid[j];
            }
            atomicAdd(&lds_cnt[cid[0]], 1.0f);
        }
    }

    atomicAdd(&lds_psum[lane * 4 + 0], r0);
    atomicAdd(&lds_psum[lane * 4 + 1], r1);
    atomicAdd(&lds_psum[lane * 4 + 2], r2);
    atomicAdd(&lds_psum[lane * 4 + 3], r3);
    __syncthreads();
    if (t < E_EXP) {
        atomicAdd(&g_psum[t], lds_psum[t]);
        atomicAdd(&g_cnt[t], lds_cnt[t]);
    }
}

// ---------------------------------------------------------------------------
// Kernel 3: aux_loss = E * sum_e (cnt_e/T) * (psum_e/T)
// ---------------------------------------------------------------------------
__global__ __launch_bounds__(256)
void aux_kernel(const float* __restrict__ g_psum, const float* __restrict__ g_cnt,
                float* __restrict__ out_aux) {
    __shared__ float red[E_EXP];
    const int t = threadIdx.x;
    const float invT = 1.0f / (float)T_TOK;
    red[t] = (g_cnt[t] * invT) * (g_psum[t] * invT);
    __syncthreads();
    #pragma unroll
    for (int s = 128; s > 0; s >>= 1) {
        if (t < s) red[t] += red[t + s];
        __syncthreads();
    }
    if (t == 0) out_aux[0] = (float)E_EXP * red[0];
}

// ---------------------------------------------------------------------------
extern "C" void kernel_launch(void* const* d_in, const int* in_sizes, int n_in,
                              void* d_out, int out_size, void* d_ws, size_t ws_size,
                              hipStream_t stream) {
    const float* x = (const float*)d_in[0];
    const float* W = (const float*)d_in[1];

    float* out = (float*)d_out;
    float* out_w = out;                       // 16384*8
    float* out_id = out + T_TOK * 8;          // 16384*8 (ids stored as floats)
    float* out_aux = out + 2 * T_TOK * 8;     // 1

    float* g_psum = (float*)d_ws;             // 256
    float* g_cnt = g_psum + E_EXP;            // 256
    float* logits = g_psum + 512;             // 16384*256 fp32 = 16 MB

    zero512_kernel<<<1, 512, 0, stream>>>(g_psum);
    gemm_kernel<<<T_TOK / MT, 256, 0, stream>>>(x, W, logits);
    router_kernel<<<T_TOK / (4 * TOKS_PER_WAVE), 256, 0, stream>>>(
        logits, out_w, out_id, g_psum, g_cnt);
    aux_kernel<<<1, 256, 0, stream>>>(g_psum, g_cnt, out_aux);
}

// Round 3
// 639.664 us; speedup vs baseline: 1.3022x; 1.3022x over previous
//
#include <hip/hip_runtime.h>
#include <hip/hip_bf16.h>
#include <stdint.h>

#define T_TOK 16384
#define D_DIM 4096
#define E_EXP 256

typedef __attribute__((ext_vector_type(8))) short bf16x8;
typedef __attribute__((ext_vector_type(4))) float f32x4;

__device__ __forceinline__ uint32_t bf16_rne(float f) {
    uint32_t u = __float_as_uint(f);
    return (u + 0x7FFFu + ((u >> 16) & 1u)) >> 16;
}

// ---------------------------------------------------------------------------
// Kernel 0: split W into 3 bf16 terms (h+m+l, RNE at each level) + zero accs.
// x = h + m + l with |residual| <= 2^-27|x|  (bf16 exponent = fp32: no
// subnormal hazard at any magnitude).
// ---------------------------------------------------------------------------
__global__ __launch_bounds__(256)
void wsplit_kernel(const float* __restrict__ W, uint16_t* __restrict__ Wh,
                   uint16_t* __restrict__ Wm, uint16_t* __restrict__ Wl,
                   float* __restrict__ acc512) {
    const int idx = blockIdx.x * 256 + threadIdx.x;  // 0..262143 float4s
    const float4 v = ((const float4*)W)[idx];
    const float f[4] = {v.x, v.y, v.z, v.w};
    uint32_t h[4], m[4], l[4];
    #pragma unroll
    for (int j = 0; j < 4; ++j) {
        h[j] = bf16_rne(f[j]);
        const float r1 = f[j] - __uint_as_float(h[j] << 16);  // exact
        m[j] = bf16_rne(r1);
        const float r2 = r1 - __uint_as_float(m[j] << 16);    // exact
        l[j] = bf16_rne(r2);
    }
    ((uint2*)Wh)[idx] = make_uint2(h[0] | (h[1] << 16), h[2] | (h[3] << 16));
    ((uint2*)Wm)[idx] = make_uint2(m[0] | (m[1] << 16), m[2] | (m[3] << 16));
    ((uint2*)Wl)[idx] = make_uint2(l[0] | (l[1] << 16), l[2] | (l[3] << 16));
    if (blockIdx.x == 0) {
        acc512[threadIdx.x] = 0.0f;
        acc512[threadIdx.x + 256] = 0.0f;
    }
}

// ---------------------------------------------------------------------------
// Kernel 1: logits = x @ W^T via split-3 bf16, 6 MFMA products per tile
// (hh, hm, mh, mm, hl, lh). Block 256 = 4 waves; tile 64 tok x 256 exp;
// each wave: 64 tok x 64 exp = 4 mt x 4 nt of 16x16x32. BK=64. W is read
// exactly once per block (straight from L2); x staged pre-split in LDS.
// ---------------------------------------------------------------------------
#define LDK 72

__global__ __launch_bounds__(256, 1)
void gemm_kernel(const float* __restrict__ x, const uint16_t* __restrict__ Wh,
                 const uint16_t* __restrict__ Wm, const uint16_t* __restrict__ Wl,
                 float* __restrict__ logits) {
    __shared__ uint16_t sXh[64 * LDK];
    __shared__ uint16_t sXm[64 * LDK];
    __shared__ uint16_t sXl[64 * LDK];
    const int t = threadIdx.x;
    const int tok0 = blockIdx.x * 64;
    const int wave = t >> 6, lane = t & 63;
    const int quad = lane >> 4, l16 = lane & 15;

    // staging: thread -> (token, 16 consecutive k)
    const int stok = t >> 2;
    const int skoff = (t & 3) * 16;
    const float* xp = x + (size_t)(tok0 + stok) * D_DIM + skoff;
    const int swoff = stok * LDK + skoff;

    uint32_t woff[4];
    #pragma unroll
    for (int nt = 0; nt < 4; ++nt)
        woff[nt] = (uint32_t)(wave * 64 + nt * 16 + l16) * D_DIM + quad * 8;

    const f32x4 zf = {0.f, 0.f, 0.f, 0.f};
    f32x4 acc[4][4];
    #pragma unroll
    for (int mt = 0; mt < 4; ++mt)
        #pragma unroll
        for (int nt = 0; nt < 4; ++nt) acc[mt][nt] = zf;

    float4 p[4];
    #pragma unroll
    for (int j = 0; j < 4; ++j) p[j] = ((const float4*)xp)[j];

    for (int kb = 0; kb < D_DIM; kb += 64) {
        // split current x tile into bf16 h/m/l and stage to LDS
        #pragma unroll
        for (int oct = 0; oct < 2; ++oct) {
            const float4 a = p[2 * oct], b = p[2 * oct + 1];
            const float f[8] = {a.x, a.y, a.z, a.w, b.x, b.y, b.z, b.w};
            uint32_t h[8], m[8], l[8];
            #pragma unroll
            for (int j = 0; j < 8; ++j) {
                h[j] = bf16_rne(f[j]);
                const float r1 = f[j] - __uint_as_float(h[j] << 16);
                m[j] = bf16_rne(r1);
                const float r2 = r1 - __uint_as_float(m[j] << 16);
                l[j] = bf16_rne(r2);
            }
            uint4 hv, mv, lv;
            hv.x = h[0] | (h[1] << 16); hv.y = h[2] | (h[3] << 16);
            hv.z = h[4] | (h[5] << 16); hv.w = h[6] | (h[7] << 16);
            mv.x = m[0] | (m[1] << 16); mv.y = m[2] | (m[3] << 16);
            mv.z = m[4] | (m[5] << 16); mv.w = m[6] | (m[7] << 16);
            lv.x = l[0] | (l[1] << 16); lv.y = l[2] | (l[3] << 16);
            lv.z = l[4] | (l[5] << 16); lv.w = l[6] | (l[7] << 16);
            *(uint4*)&sXh[swoff + oct * 8] = hv;
            *(uint4*)&sXm[swoff + oct * 8] = mv;
            *(uint4*)&sXl[swoff + oct * 8] = lv;
        }
        // prefetch next x tile (stays in flight across this tile's compute)
        if (kb + 64 < D_DIM) {
            const float* xn = xp + kb + 64;
            #pragma unroll
            for (int j = 0; j < 4; ++j) p[j] = ((const float4*)xn)[j];
        }
        __syncthreads();

        #pragma unroll
        for (int s = 0; s < 2; ++s) {
            bf16x8 ah[4], am[4], al[4], bh[4], bm[4], bl[4];
            #pragma unroll
            for (int nt = 0; nt < 4; ++nt) {
                const uint32_t o = woff[nt] + kb + s * 32;
                bh[nt] = *(const bf16x8*)(Wh + o);
                bm[nt] = *(const bf16x8*)(Wm + o);
                bl[nt] = *(const bf16x8*)(Wl + o);
            }
            #pragma unroll
            for (int mt = 0; mt < 4; ++mt) {
                const int ro = (mt * 16 + l16) * LDK + s * 32 + quad * 8;
                ah[mt] = *(const bf16x8*)&sXh[ro];
                am[mt] = *(const bf16x8*)&sXm[ro];
                al[mt] = *(const bf16x8*)&sXl[ro];
            }
            #pragma unroll
            for (int mt = 0; mt < 4; ++mt)
                #pragma unroll
                for (int nt = 0; nt < 4; ++nt) {
                    f32x4 c = acc[mt][nt];
                    c = __builtin_amdgcn_mfma_f32_16x16x32_bf16(ah[mt], bh[nt], c, 0, 0, 0);
                    c = __builtin_amdgcn_mfma_f32_16x16x32_bf16(ah[mt], bm[nt], c, 0, 0, 0);
                    c = __builtin_amdgcn_mfma_f32_16x16x32_bf16(am[mt], bh[nt], c, 0, 0, 0);
                    c = __builtin_amdgcn_mfma_f32_16x16x32_bf16(am[mt], bm[nt], c, 0, 0, 0);
                    c = __builtin_amdgcn_mfma_f32_16x16x32_bf16(ah[mt], bl[nt], c, 0, 0, 0);
                    c = __builtin_amdgcn_mfma_f32_16x16x32_bf16(al[mt], bh[nt], c, 0, 0, 0);
                    acc[mt][nt] = c;
                }
        }
        __syncthreads();
    }

    // epilogue: C/D layout col=lane&15, row=quad*4+reg
    #pragma unroll
    for (int mt = 0; mt < 4; ++mt)
        #pragma unroll
        for (int nt = 0; nt < 4; ++nt)
            #pragma unroll
            for (int r = 0; r < 4; ++r)
                logits[(size_t)(tok0 + mt * 16 + quad * 4 + r) * E_EXP +
                       wave * 64 + nt * 16 + l16] = acc[mt][nt][r];
}

// ---------------------------------------------------------------------------
// Kernel 2: per-token softmax + grouped top-k (one wave per token).
// ---------------------------------------------------------------------------
__device__ __forceinline__ float wave_max(float v) {
    #pragma unroll
    for (int off = 32; off >= 1; off >>= 1)
        v = fmaxf(v, __shfl_xor(v, off, 64));
    return v;
}
__device__ __forceinline__ float wave_sum(float v) {
    #pragma unroll
    for (int off = 32; off >= 1; off >>= 1)
        v += __shfl_xor(v, off, 64);
    return v;
}

#define TOKS_PER_WAVE 4

__global__ __launch_bounds__(256)
void router_kernel(const float* __restrict__ logits,
                   float* __restrict__ out_w,
                   float* __restrict__ out_id,
                   float* __restrict__ g_psum,
                   float* __restrict__ g_cnt) {
    __shared__ float lds_psum[E_EXP];
    __shared__ float lds_cnt[E_EXP];
    const int t = threadIdx.x;
    lds_psum[t] = 0.0f; lds_cnt[t] = 0.0f;
    __syncthreads();

    const int wave = t >> 6;
    const int lane = t & 63;
    const int tok0 = blockIdx.x * (4 * TOKS_PER_WAVE) + wave * TOKS_PER_WAVE;

    float r0 = 0.f, r1 = 0.f, r2 = 0.f, r3 = 0.f;

    for (int it = 0; it < TOKS_PER_WAVE; ++it) {
        const int tok = tok0 + it;
        const float4 lg = *(const float4*)(logits + (size_t)tok * E_EXP + lane * 4);

        const float M = wave_max(fmaxf(fmaxf(lg.x, lg.y), fmaxf(lg.z, lg.w)));
        float p0 = __expf(lg.x - M);
        float p1 = __expf(lg.y - M);
        float p2 = __expf(lg.z - M);
        float p3 = __expf(lg.w - M);
        const float inv = 1.0f / wave_sum(p0 + p1 + p2 + p3);
        p0 *= inv; p1 *= inv; p2 *= inv; p3 *= inv;
        r0 += p0; r1 += p1; r2 += p2; r3 += p3;

        // per-lane top-2 of 4 (ties -> lowest index, matching lax.top_k)
        const int e0 = lane * 4;
        float v1 = p0, v2 = p1; int i1 = e0, i2 = e0 + 1;
        if (p1 > p0) { v1 = p1; i1 = e0 + 1; v2 = p0; i2 = e0; }
        if (p2 > v1)      { v2 = v1; i2 = i1; v1 = p2; i1 = e0 + 2; }
        else if (p2 > v2) { v2 = p2; i2 = e0 + 2; }
        if (p3 > v1)      { v2 = v1; i2 = i1; v1 = p3; i1 = e0 + 3; }
        else if (p3 > v2) { v2 = p3; i2 = e0 + 3; }

        // merge top-2 across the 8 lanes of each group
        #pragma unroll
        for (int off = 1; off <= 4; off <<= 1) {
            const float ov1 = __shfl_xor(v1, off, 64);
            const int   oi1 = __shfl_xor(i1, off, 64);
            const float ov2 = __shfl_xor(v2, off, 64);
            const int   oi2 = __shfl_xor(i2, off, 64);
            float n1, n2; int ni1, ni2;
            const bool o_first = (ov1 > v1) || (ov1 == v1 && oi1 < i1);
            if (o_first) {
                n1 = ov1; ni1 = oi1;
                const bool s = (ov2 > v1) || (ov2 == v1 && oi2 < i1);
                n2 = s ? ov2 : v1; ni2 = s ? oi2 : i1;
            } else {
                n1 = v1; ni1 = i1;
                const bool s = (ov1 > v2) || (ov1 == v2 && oi1 < i2);
                n2 = s ? ov1 : v2; ni2 = s ? oi1 : i2;
            }
            v1 = n1; i1 = ni1; v2 = n2; i2 = ni2;
        }

        // gather all 8 groups' results to every lane
        float gv1[8], gv2[8], gsc[8]; int gi1[8], gi2[8];
        #pragma unroll
        for (int g = 0; g < 8; ++g) {
            gv1[g] = __shfl(v1, g * 8, 64);
            gv2[g] = __shfl(v2, g * 8, 64);
            gi1[g] = __shfl(i1, g * 8, 64);
            gi2[g] = __shfl(i2, g * 8, 64);
            gsc[g] = gv1[g] + gv2[g];
        }

        // top-4 groups by score (ties -> lowest group index)
        float cp[8]; int cid[8];
        int usedmask = 0;
        #pragma unroll
        for (int r = 0; r < 4; ++r) {
            float best = -1.0f; int bg = 0;
            float b1 = 0.f, b2 = 0.f; int bi1 = 0, bi2 = 0;
            #pragma unroll
            for (int g = 0; g < 8; ++g) {
                const bool ok = (((usedmask >> g) & 1) == 0) && (gsc[g] > best);
                if (ok) { best = gsc[g]; bg = g;
                          b1 = gv1[g]; b2 = gv2[g]; bi1 = gi1[g]; bi2 = gi2[g]; }
            }
            usedmask |= (1 << bg);
            cp[2 * r] = b1; cp[2 * r + 1] = b2;
            cid[2 * r] = bi1; cid[2 * r + 1] = bi2;
        }

        float wsum = 1e-9f;
        #pragma unroll
        for (int j = 0; j < 8; ++j) wsum += cp[j];
        const float winv = 1.0f / wsum;

        if (lane == 0) {
            #pragma unroll
            for (int j = 0; j < 8; ++j) {
                out_w[(size_t)tok * 8 + j] = cp[j] * winv;
                out_id[(size_t)tok * 8 + j] = (float)cid[j];
            }
            atomicAdd(&lds_cnt[cid[0]], 1.0f);
        }
    }

    atomicAdd(&lds_psum[lane * 4 + 0], r0);
    atomicAdd(&lds_psum[lane * 4 + 1], r1);
    atomicAdd(&lds_psum[lane * 4 + 2], r2);
    atomicAdd(&lds_psum[lane * 4 + 3], r3);
    __syncthreads();
    atomicAdd(&g_psum[t], lds_psum[t]);
    atomicAdd(&g_cnt[t], lds_cnt[t]);
}

// ---------------------------------------------------------------------------
// Kernel 3: aux_loss = E * sum_e (cnt_e/T) * (psum_e/T)
// ---------------------------------------------------------------------------
__global__ __launch_bounds__(256)
void aux_kernel(const float* __restrict__ g_psum, const float* __restrict__ g_cnt,
                float* __restrict__ out_aux) {
    __shared__ float red[E_EXP];
    const int t = threadIdx.x;
    const float invT = 1.0f / (float)T_TOK;
    red[t] = (g_cnt[t] * invT) * (g_psum[t] * invT);
    __syncthreads();
    #pragma unroll
    for (int s = 128; s > 0; s >>= 1) {
        if (t < s) red[t] += red[t + s];
        __syncthreads();
    }
    if (t == 0) out_aux[0] = (float)E_EXP * red[0];
}

// ---------------------------------------------------------------------------
extern "C" void kernel_launch(void* const* d_in, const int* in_sizes, int n_in,
                              void* d_out, int out_size, void* d_ws, size_t ws_size,
                              hipStream_t stream) {
    const float* x = (const float*)d_in[0];
    const float* W = (const float*)d_in[1];

    float* out = (float*)d_out;
    float* out_w = out;                       // 16384*8
    float* out_id = out + T_TOK * 8;          // 16384*8 (ids stored as floats)
    float* out_aux = out + 2 * T_TOK * 8;     // 1

    float* g_psum = (float*)d_ws;                       // 256
    float* g_cnt = g_psum + E_EXP;                      // 256
    float* logits = g_psum + 512;                       // 16 MB
    uint16_t* Wh = (uint16_t*)(logits + (size_t)T_TOK * E_EXP);  // 2 MB
    uint16_t* Wm = Wh + (size_t)E_EXP * D_DIM;                   // 2 MB
    uint16_t* Wl = Wm + (size_t)E_EXP * D_DIM;                   // 2 MB

    wsplit_kernel<<<1024, 256, 0, stream>>>(W, Wh, Wm, Wl, g_psum);
    gemm_kernel<<<T_TOK / 64, 256, 0, stream>>>(x, Wh, Wm, Wl, logits);
    router_kernel<<<T_TOK / (4 * TOKS_PER_WAVE), 256, 0, stream>>>(
        logits, out_w, out_id, g_psum, g_cnt);
    aux_kernel<<<1, 256, 0, stream>>>(g_psum, g_cnt, out_aux);
}